// Round 8
// baseline (1713.362 us; speedup 1.0000x reference)
//
#include <hip/hip_runtime.h>

// Fused 3-layer LSTM + dense head, layer-pipelined wave specialization.
// B=2048, T=256, F=64, H=[64,32,16], OUT=1. fp32 in/out.
//
// bf16 3-term split MFMA (ah*wh + al*wh + ah*wl) for ~2^-16 precision.
// Block = 512 threads = 8 waves. Round-14: BT=4, grid=512 -> 2 independent
// blocks per CU (4 waves/SIMD). R1's 302us structure is TLP-starved: 2
// waves/SIMD, all barrier-locked each step -> SIMD idles whenever both
// waves sit in LDS-latency/trans chains or barrier drain (MfmaUtil 45 +
// VALU 38 but step ~2x its issue content). Two blocks share no barrier, so
// one block's drain is filled by the other's compute. Per-CU issue load
// doubles (VALU ~2120cy, MFMA ~840cy per step-pair), still under the old
// 2810cy step -> step-pair approaches the VALU-issue bound.
// R7's setprio + split-acc are reverted (both hurt: prio-1 compute waves
// starved the prio-0 stager; lockstep structure = m190's regression case).
//   waves 0-3 : layer0 at step t    waves 4-5 : layer1 at t-1
//   wave  6   : layer2 at t-2       wave  7   : x-stager (lanes 0-31 only)
// Rows 4..7 of the 16-row MFMA M-dim are zero-input padding (finite zero
// trajectory, row-isolated in MFMA); dense head reads rows 0..3.

typedef __attribute__((ext_vector_type(8))) short s8v;   // 8 x bf16
typedef __attribute__((ext_vector_type(4))) float f4v;   // 4 x f32
typedef unsigned short ushort_t;

#define T_STEPS 256
#define BT 4

// SMEM layout (units: shorts). chunk = [kgrp 0..3][row 0..15][j 0..7] = 512 shorts.
#define XH  0       // [par][2 chunks], parity stride 1024
#define XL  2048
#define H0H 4096    // [par][2 chunks], parity stride 1024
#define H0L 6144
#define H1H 8192    // [par][1 chunk],  parity stride 512
#define H1L 9216
#define H2H 10240   // [par][1 chunk],  parity stride 512 (k 16..31 = zero pad)
#define H2L 11264
#define SM_SHORTS 12288

#define PIN(v) asm volatile("" : "+v"(v))
#define BAR()  asm volatile("s_waitcnt lgkmcnt(0)\n\ts_barrier" ::: "memory")

__device__ __forceinline__ unsigned short f2bf(float f) {      // RTNE (weights, one-time)
    unsigned u = __float_as_uint(f);
    u += 0x7fff + ((u >> 16) & 1);
    return (unsigned short)(u >> 16);
}
__device__ __forceinline__ float bf2f(unsigned short s) {
    return __uint_as_float(((unsigned)s) << 16);
}
// cheap truncation split: hi = top 16 bits, lo = trunc(v - hi). Error <= 2^-16*|v|.
__device__ __forceinline__ void tsplit(float v, unsigned short& hi, unsigned short& lo) {
    unsigned u = __float_as_uint(v);
    hi = (unsigned short)(u >> 16);
    float r = v - __uint_as_float(u & 0xffff0000u);   // exact
    lo = (unsigned short)(__float_as_uint(r) >> 16);
}
__device__ __forceinline__ float sigmoid_f(float x) {
    return __builtin_amdgcn_rcpf(1.0f + __expf(-x));
}
__device__ __forceinline__ float tanh_f(float x) {
    return 1.0f - 2.0f * __builtin_amdgcn_rcpf(__expf(2.0f * x) + 1.0f);
}

// combined [W;U] weight element, zero-padded past KH rows
__device__ __forceinline__ float wval(const float* W, const float* U,
                                      int inDim, int KH, int fourH, int k, int n) {
    if (k < inDim) return W[k * fourH + n];
    if (k < KH)    return U[(k - inDim) * fourH + n];
    return 0.0f;
}
__device__ __forceinline__ void load_bfrag(const float* W, const float* U,
                                           int inDim, int KH, int fourH,
                                           int k0, int n, s8v& hi, s8v& lo) {
#pragma unroll
    for (int j = 0; j < 8; ++j) {
        float w = wval(W, U, inDim, KH, fourH, k0 + j, n);
        unsigned short h = f2bf(w);
        unsigned short l = f2bf(w - bf2f(h));
        hi[j] = (short)h;
        lo[j] = (short)l;
    }
}

// Gate math on 2 rows/lane after full-wave redistribution:
//   low lanes (fr<2)  : own regs {0,1}       -> rows fr*4 + {0,1}
//   high lanes (fr>=2): partner regs {2,3}   -> rows (fr-2)*4 + {2,3}
__device__ __forceinline__ void gates2(const f4v* acc, bool low, float* c, float* hn) {
#pragma unroll
    for (int j = 0; j < 2; ++j) {
        float si = __shfl_xor(acc[0][j + 2], 32);
        float sf = __shfl_xor(acc[1][j + 2], 32);
        float sg = __shfl_xor(acc[2][j + 2], 32);
        float so = __shfl_xor(acc[3][j + 2], 32);
        float zi = low ? acc[0][j] : si;
        float zf = low ? acc[1][j] : sf;
        float zg = low ? acc[2][j] : sg;
        float zo = low ? acc[3][j] : so;
        float ig = sigmoid_f(zi);
        float fg = sigmoid_f(zf);
        float gg = tanh_f(zg);
        float og = sigmoid_f(zo);
        c[j] = fmaf(fg, c[j], ig * gg);
        hn[j] = og * tanh_f(c[j]);
    }
}

__global__ __attribute__((amdgpu_flat_work_group_size(512, 512),
                          amdgpu_waves_per_eu(4, 4)))
void lstm_pipe(const float* __restrict__ x,
               const float* __restrict__ W0, const float* __restrict__ U0, const float* __restrict__ b0,
               const float* __restrict__ W1, const float* __restrict__ U1, const float* __restrict__ b1,
               const float* __restrict__ W2, const float* __restrict__ U2, const float* __restrict__ b2,
               const float* __restrict__ Wd, const float* __restrict__ bd,
               float* __restrict__ out)
{
    const int tid  = threadIdx.x;
    const int lane = tid & 63;
    const int wv   = tid >> 6;          // 0..7
    const int fr   = lane >> 4;         // k-group / C row-group
    const int fc   = lane & 15;         // frag column
    const int bbase = blockIdx.x * BT;

    __shared__ __align__(16) ushort_t SMEM[SM_SHORTS];
    __shared__ __align__(16) float h2last[8][16];       // rows 4..7 = padding junk

    // zero all staging (rows 4..15 of every chunk must stay zero; h init = 0)
    {
        unsigned* p32 = (unsigned*)SMEM;
        for (int i = tid; i < SM_SHORTS / 2; i += 512) p32[i] = 0u;
    }
    __syncthreads();                                    // barrier #1

    const ushort_t* rb = SMEM + lane * 8;               // frag read base (all roles)
    const bool low = (lane < 32);
    const int rowb = (fr & 1) * 4 + ((fr >> 1) << 1);   // this lane's h row base (0,4,2,6)

    if (wv < 4) {
        // =================== layer0 role (waves 0..3) ===================
        s8v Bh[4][4], Bl[4][4];                         // [gate][kc]
        float bias[4];
#pragma unroll
        for (int g = 0; g < 4; ++g) {
            int n = g * 64 + wv * 16 + fc;
            bias[g] = b0[n];
#pragma unroll
            for (int kc = 0; kc < 4; ++kc)
                load_bfrag(W0, U0, 64, 128, 256, kc * 32 + fr * 8, n, Bh[g][kc], Bl[g][kc]);
        }
#pragma unroll
        for (int g = 0; g < 4; ++g) {
            PIN(bias[g]);
#pragma unroll
            for (int kc = 0; kc < 4; ++kc) { PIN(Bh[g][kc]); PIN(Bl[g][kc]); }
        }
        float c0[2] = {0.f, 0.f};
        const int hq  = wv >> 1;                        // h0 chunk this wave writes
        const int k   = (wv & 1) * 16 + fc;             // k within chunk
        const int ibw = (k >> 3) * 128 + (k & 7);       // lane-dep write offset
        __syncthreads();                                // barrier #2
        for (int s = 0; s < T_STEPS + 2; ++s) {
            if (s < T_STEPS) {
                const ushort_t* r = rb + ((s & 1) << 10);   // parity*1024 shorts
                s8v ah[4], al[4];
                ah[0] = *(const s8v*)&r[XH  +   0];
                al[0] = *(const s8v*)&r[XL  +   0];
                ah[1] = *(const s8v*)&r[XH  + 512];
                al[1] = *(const s8v*)&r[XL  + 512];
                ah[2] = *(const s8v*)&r[H0H +   0];
                al[2] = *(const s8v*)&r[H0L +   0];
                ah[3] = *(const s8v*)&r[H0H + 512];
                al[3] = *(const s8v*)&r[H0L + 512];
                f4v acc[4];
#pragma unroll
                for (int g = 0; g < 4; ++g) acc[g] = (f4v){bias[g], bias[g], bias[g], bias[g]};
                // same-acc distance 4: latency hidden by the 4 independent g chains
#pragma unroll
                for (int kc = 0; kc < 4; ++kc) {
#pragma unroll
                    for (int g = 0; g < 4; ++g)
                        acc[g] = __builtin_amdgcn_mfma_f32_16x16x32_bf16(ah[kc], Bh[g][kc], acc[g], 0, 0, 0);
#pragma unroll
                    for (int g = 0; g < 4; ++g)
                        acc[g] = __builtin_amdgcn_mfma_f32_16x16x32_bf16(al[kc], Bh[g][kc], acc[g], 0, 0, 0);
#pragma unroll
                    for (int g = 0; g < 4; ++g)
                        acc[g] = __builtin_amdgcn_mfma_f32_16x16x32_bf16(ah[kc], Bl[g][kc], acc[g], 0, 0, 0);
                }
                float hn[2];
                gates2(acc, low, c0, hn);
                {
                    ushort_t* w = SMEM + (((s & 1) ^ 1) << 10) + hq * 512 + ibw;
#pragma unroll
                    for (int j = 0; j < 2; ++j) {
                        unsigned short hh_, ll_;
                        tsplit(hn[j], hh_, ll_);
                        w[H0H + (rowb + j) * 8] = hh_;
                        w[H0L + (rowb + j) * 8] = ll_;
                    }
                }
            }
            BAR();
        }
    } else if (wv < 6) {
        // =================== layer1 role (waves 4,5) ===================
        s8v Bh[4][3], Bl[4][3];
        float bias[4];
#pragma unroll
        for (int g = 0; g < 4; ++g) {
            int n = g * 32 + (wv & 1) * 16 + fc;
            bias[g] = b1[n];
#pragma unroll
            for (int kc = 0; kc < 3; ++kc)
                load_bfrag(W1, U1, 64, 96, 128, kc * 32 + fr * 8, n, Bh[g][kc], Bl[g][kc]);
        }
#pragma unroll
        for (int g = 0; g < 4; ++g) {
            PIN(bias[g]);
#pragma unroll
            for (int kc = 0; kc < 3; ++kc) { PIN(Bh[g][kc]); PIN(Bl[g][kc]); }
        }
        float c1[2] = {0.f, 0.f};
        const int k   = (wv & 1) * 16 + fc;
        const int ibw = (k >> 3) * 128 + (k & 7);
        __syncthreads();                                // barrier #2
        for (int s = 0; s < T_STEPS + 2; ++s) {
            if (s >= 1 && s <= T_STEPS) {
                const int p = s & 1;
                const ushort_t* r  = rb + (p << 10);    // H0 parity stride 1024
                const ushort_t* r1 = rb + (p << 9);     // H1 parity stride 512
                s8v ah[3], al[3];
                ah[0] = *(const s8v*)&r[H0H +   0];
                al[0] = *(const s8v*)&r[H0L +   0];
                ah[1] = *(const s8v*)&r[H0H + 512];
                al[1] = *(const s8v*)&r[H0L + 512];
                ah[2] = *(const s8v*)&r1[H1H];
                al[2] = *(const s8v*)&r1[H1L];
                f4v acc[4];
#pragma unroll
                for (int g = 0; g < 4; ++g) acc[g] = (f4v){bias[g], bias[g], bias[g], bias[g]};
#pragma unroll
                for (int kc = 0; kc < 3; ++kc) {
#pragma unroll
                    for (int g = 0; g < 4; ++g)
                        acc[g] = __builtin_amdgcn_mfma_f32_16x16x32_bf16(ah[kc], Bh[g][kc], acc[g], 0, 0, 0);
#pragma unroll
                    for (int g = 0; g < 4; ++g)
                        acc[g] = __builtin_amdgcn_mfma_f32_16x16x32_bf16(al[kc], Bh[g][kc], acc[g], 0, 0, 0);
#pragma unroll
                    for (int g = 0; g < 4; ++g)
                        acc[g] = __builtin_amdgcn_mfma_f32_16x16x32_bf16(ah[kc], Bl[g][kc], acc[g], 0, 0, 0);
                }
                float hn[2];
                gates2(acc, low, c1, hn);
                {
                    ushort_t* w = SMEM + ((p ^ 1) << 9) + ibw;
#pragma unroll
                    for (int j = 0; j < 2; ++j) {
                        unsigned short hh_, ll_;
                        tsplit(hn[j], hh_, ll_);
                        w[H1H + (rowb + j) * 8] = hh_;
                        w[H1L + (rowb + j) * 8] = ll_;
                    }
                }
            }
            BAR();
        }
    } else if (wv == 6) {
        // =================== layer2 role (wave 6) ===================
        s8v Bh[4][2], Bl[4][2];
        float bias[4];
#pragma unroll
        for (int g = 0; g < 4; ++g) {
            int n = g * 16 + fc;
            bias[g] = b2[n];
#pragma unroll
            for (int kc = 0; kc < 2; ++kc)
                load_bfrag(W2, U2, 32, 48, 64, kc * 32 + fr * 8, n, Bh[g][kc], Bl[g][kc]);
        }
#pragma unroll
        for (int g = 0; g < 4; ++g) {
            PIN(bias[g]);
#pragma unroll
            for (int kc = 0; kc < 2; ++kc) { PIN(Bh[g][kc]); PIN(Bl[g][kc]); }
        }
        float c2[2] = {0.f, 0.f};
        const int ibw = (fc >> 3) * 128 + (fc & 7);     // k = fc (0..15)
        __syncthreads();                                // barrier #2
        for (int s = 0; s < T_STEPS + 2; ++s) {
            if (s >= 2) {
                const int p = s & 1;
                const ushort_t* r1 = rb + (p << 9);     // H1,H2 parity stride 512
                s8v ah[2], al[2];
                ah[0] = *(const s8v*)&r1[H1H];
                al[0] = *(const s8v*)&r1[H1L];
                ah[1] = *(const s8v*)&r1[H2H];
                al[1] = *(const s8v*)&r1[H2L];
                f4v acc[4];
#pragma unroll
                for (int g = 0; g < 4; ++g) acc[g] = (f4v){bias[g], bias[g], bias[g], bias[g]};
#pragma unroll
                for (int kc = 0; kc < 2; ++kc) {
#pragma unroll
                    for (int g = 0; g < 4; ++g)
                        acc[g] = __builtin_amdgcn_mfma_f32_16x16x32_bf16(ah[kc], Bh[g][kc], acc[g], 0, 0, 0);
#pragma unroll
                    for (int g = 0; g < 4; ++g)
                        acc[g] = __builtin_amdgcn_mfma_f32_16x16x32_bf16(al[kc], Bh[g][kc], acc[g], 0, 0, 0);
#pragma unroll
                    for (int g = 0; g < 4; ++g)
                        acc[g] = __builtin_amdgcn_mfma_f32_16x16x32_bf16(ah[kc], Bl[g][kc], acc[g], 0, 0, 0);
                }
                float hn[2];
                gates2(acc, low, c2, hn);
                {
                    ushort_t* w = SMEM + ((p ^ 1) << 9) + ibw;
#pragma unroll
                    for (int j = 0; j < 2; ++j) {
                        unsigned short hh_, ll_;
                        tsplit(hn[j], hh_, ll_);
                        w[H2H + (rowb + j) * 8] = hh_;
                        w[H2L + (rowb + j) * 8] = ll_;
                    }
                    if (s == T_STEPS + 1) {             // t2 = 255: final h2
#pragma unroll
                        for (int j = 0; j < 2; ++j) h2last[rowb + j][fc] = hn[j];
                    }
                }
            }
            BAR();
        }
    } else {
        // =================== x-stager role (wave 7), 2-deep pipeline ===================
        // BT=4: only lanes with xb<4 (lanes 0..31) are active; x rows 4..7 of
        // the staging chunks stay zero from the init memset.
        const int xb = lane >> 3;                       // batch row 0..7
        const int fo = (lane & 7) * 8;                  // feature octet base
        const bool act = (xb < BT);
        const float* xp = x + ((size_t)(bbase + (act ? xb : 0)) * T_STEPS) * 64 + fo;
        const int o2 = (fo >> 5) * 512 + (((fo & 31) >> 3) * 16 + xb) * 8;

        auto write_x = [&](float4 v0, float4 v1, int tt) {
            if (!act) return;
            float vv[8] = {v0.x, v0.y, v0.z, v0.w, v1.x, v1.y, v1.z, v1.w};
            s8v hi8, lo8;
#pragma unroll
            for (int j = 0; j < 8; ++j) {
                unsigned short h_, l_;
                tsplit(vv[j], h_, l_);
                hi8[j] = (short)h_;
                lo8[j] = (short)l_;
            }
            ushort_t* wbp = SMEM + ((tt & 1) << 10) + o2;
            *(s8v*)&wbp[XH] = hi8;
            *(s8v*)&wbp[XL] = lo8;
        };

        // prologue: write x(0), prefetch x(1) into regs
        float4 pa = *(const float4*)(xp);
        float4 pb = *(const float4*)(xp + 4);
        write_x(pa, pb, 0);
        pa = *(const float4*)(xp + 64);
        pb = *(const float4*)(xp + 64 + 4);
        __syncthreads();                                // barrier #2
        for (int s = 0; s < T_STEPS + 2; ++s) {
            float4 na, nb;
            const bool ld = (s + 2 < T_STEPS);
            if (ld) {                                   // issue x(s+2) early
                na = *(const float4*)(xp + (size_t)(s + 2) * 64);
                nb = *(const float4*)(xp + (size_t)(s + 2) * 64 + 4);
            }
            if (s + 1 < T_STEPS) write_x(pa, pb, s + 1);   // waits on load from s-1
            if (ld) { pa = na; pb = nb; }
            BAR();
        }
    }

    __syncthreads();
    // =================== dense head ===================
    if (tid < BT) {
        float acc = bd[0];
#pragma unroll
        for (int j = 0; j < 16; ++j) acc += h2last[tid][j] * Wd[j];
        out[bbase + tid] = acc;
    }
}

extern "C" void kernel_launch(void* const* d_in, const int* in_sizes, int n_in,
                              void* d_out, int out_size, void* d_ws, size_t ws_size,
                              hipStream_t stream) {
    (void)in_sizes; (void)n_in; (void)d_ws; (void)ws_size; (void)out_size;
    const float* x  = (const float*)d_in[0];
    const float* W0 = (const float*)d_in[1];
    const float* U0 = (const float*)d_in[2];
    const float* b0 = (const float*)d_in[3];
    const float* W1 = (const float*)d_in[4];
    const float* U1 = (const float*)d_in[5];
    const float* b1 = (const float*)d_in[6];
    const float* W2 = (const float*)d_in[7];
    const float* U2 = (const float*)d_in[8];
    const float* b2 = (const float*)d_in[9];
    const float* Wd = (const float*)d_in[10];
    const float* bd = (const float*)d_in[11];
    float* out = (float*)d_out;

    dim3 grid(2048 / BT);   // 512 blocks, 2 per CU (4 waves/SIMD)
    dim3 block(512);        // 8 waves
    hipLaunchKernelGGL(lstm_pipe, grid, block, 0, stream,
                       x, W0, U0, b0, W1, U1, b1, W2, U2, b2, Wd, bd, out);
}

// Round 9
// 414.614 us; speedup vs baseline: 4.1324x; 4.1324x over previous
//
#include <hip/hip_runtime.h>

// Fused 3-layer LSTM + dense head, layer-pipelined wave specialization.
// B=2048, T=256, F=64, H=[64,32,16], OUT=1. fp32 in/out.
//
// bf16 3-term split MFMA (ah*wh + al*wh + ah*wl) for ~2^-16 precision.
// Block = 512 threads = 8 waves, grid = 256 (1 block/CU, BT=8 batches).
//   waves 0-3 : layer0 at step t    waves 4-5 : layer1 at t-1
//   wave  6   : layer2 at t-2       wave  7   : x-stager (t+1, 2-deep pipeline)
//
// Round-15: base = R1 (302us counters; best verified). Failed branches, kept
// for the record: z_x producer (R3/R6: hipcc re-serializes LDS-fed MFMA and
// drops frags from registers), split-acc+setprio (R7: setprio starves the
// prio-0 stager in this lockstep structure), 2 blocks/CU (R8: 128-VGPR/wave
// budget spills the resident weight frags -> 3.1GB of scratch re-reads).
// This round's single change: gates2's cross-half exchange uses
// v_permlane32_swap_b32 (VALU, ~2cy) instead of __shfl_xor(.,32) which
// lowers to ds_bpermute_b32 (LDS pipe, ~30-40cy at the gates entry).
// One swap(acc[g][j], acc[g][j+2]) = low lanes keep own reg j, high lanes
// receive partner's reg j+2 -- replaces bpermute+cndmask 2-for-1 and takes
// the LDS unit out of the gates path (56 fewer LDS-pipe ops/step/CU).
// Bit-identical data movement -> absmax unchanged.

typedef __attribute__((ext_vector_type(8))) short s8v;   // 8 x bf16
typedef __attribute__((ext_vector_type(4))) float f4v;   // 4 x f32
typedef __attribute__((ext_vector_type(2))) unsigned uint2v;
typedef unsigned short ushort_t;

#define T_STEPS 256
#define BT 8

// SMEM layout (units: shorts). chunk = [kgrp 0..3][row 0..15][j 0..7] = 512 shorts.
#define XH  0       // [par][2 chunks], parity stride 1024
#define XL  2048
#define H0H 4096    // [par][2 chunks], parity stride 1024
#define H0L 6144
#define H1H 8192    // [par][1 chunk],  parity stride 512
#define H1L 9216
#define H2H 10240   // [par][1 chunk],  parity stride 512 (k 16..31 = zero pad)
#define H2L 11264
#define SM_SHORTS 12288

#define PIN(v) asm volatile("" : "+v"(v))
#define BAR()  asm volatile("s_waitcnt lgkmcnt(0)\n\ts_barrier" ::: "memory")

__device__ __forceinline__ unsigned short f2bf(float f) {      // RTNE (weights, one-time)
    unsigned u = __float_as_uint(f);
    u += 0x7fff + ((u >> 16) & 1);
    return (unsigned short)(u >> 16);
}
__device__ __forceinline__ float bf2f(unsigned short s) {
    return __uint_as_float(((unsigned)s) << 16);
}
// cheap truncation split: hi = top 16 bits, lo = trunc(v - hi). Error <= 2^-16*|v|.
__device__ __forceinline__ void tsplit(float v, unsigned short& hi, unsigned short& lo) {
    unsigned u = __float_as_uint(v);
    hi = (unsigned short)(u >> 16);
    float r = v - __uint_as_float(u & 0xffff0000u);   // exact
    lo = (unsigned short)(__float_as_uint(r) >> 16);
}
__device__ __forceinline__ float sigmoid_f(float x) {
    return __builtin_amdgcn_rcpf(1.0f + __expf(-x));
}
__device__ __forceinline__ float tanh_f(float x) {
    return 1.0f - 2.0f * __builtin_amdgcn_rcpf(__expf(2.0f * x) + 1.0f);
}

// z[lane] = lane<32 ? a[lane] : b[lane-32] -- one v_permlane32_swap_b32.
// (swap semantics: result0 = {a[0:31], b[0:31]->hi}; result1 unused)
__device__ __forceinline__ float sel_swap(float a, float b) {
    uint2v r = __builtin_amdgcn_permlane32_swap(__float_as_uint(a), __float_as_uint(b), false, false);
    return __uint_as_float(r[0]);
}

// combined [W;U] weight element, zero-padded past KH rows
__device__ __forceinline__ float wval(const float* W, const float* U,
                                      int inDim, int KH, int fourH, int k, int n) {
    if (k < inDim) return W[k * fourH + n];
    if (k < KH)    return U[(k - inDim) * fourH + n];
    return 0.0f;
}
__device__ __forceinline__ void load_bfrag(const float* W, const float* U,
                                           int inDim, int KH, int fourH,
                                           int k0, int n, s8v& hi, s8v& lo) {
#pragma unroll
    for (int j = 0; j < 8; ++j) {
        float w = wval(W, U, inDim, KH, fourH, k0 + j, n);
        unsigned short h = f2bf(w);
        unsigned short l = f2bf(w - bf2f(h));
        hi[j] = (short)h;
        lo[j] = (short)l;
    }
}

// Gate math on 2 rows/lane after full-wave redistribution:
//   low lanes (fr<2)  : own regs {0,1}       -> rows fr*4 + {0,1}
//   high lanes (fr>=2): partner regs {2,3}   -> rows (fr-2)*4 + {2,3}
// i.e. lane's rows = (fr&1)*4 + (fr>>1)*2 + j. permlane32_swap does the
// low/high select in-register (no LDS pipe, no cndmask).
__device__ __forceinline__ void gates2(const f4v* acc, float* c, float* hn) {
#pragma unroll
    for (int j = 0; j < 2; ++j) {
        float zi = sel_swap(acc[0][j], acc[0][j + 2]);
        float zf = sel_swap(acc[1][j], acc[1][j + 2]);
        float zg = sel_swap(acc[2][j], acc[2][j + 2]);
        float zo = sel_swap(acc[3][j], acc[3][j + 2]);
        float ig = sigmoid_f(zi);
        float fg = sigmoid_f(zf);
        float gg = tanh_f(zg);
        float og = sigmoid_f(zo);
        c[j] = fmaf(fg, c[j], ig * gg);
        hn[j] = og * tanh_f(c[j]);
    }
}

__global__ __attribute__((amdgpu_flat_work_group_size(512, 512),
                          amdgpu_waves_per_eu(2, 2)))
void lstm_pipe(const float* __restrict__ x,
               const float* __restrict__ W0, const float* __restrict__ U0, const float* __restrict__ b0,
               const float* __restrict__ W1, const float* __restrict__ U1, const float* __restrict__ b1,
               const float* __restrict__ W2, const float* __restrict__ U2, const float* __restrict__ b2,
               const float* __restrict__ Wd, const float* __restrict__ bd,
               float* __restrict__ out)
{
    const int tid  = threadIdx.x;
    const int lane = tid & 63;
    const int wv   = tid >> 6;          // 0..7
    const int fr   = lane >> 4;         // k-group / C row-group
    const int fc   = lane & 15;         // frag column
    const int bbase = blockIdx.x * BT;

    __shared__ __align__(16) ushort_t SMEM[SM_SHORTS];
    __shared__ __align__(16) float h2last[BT][16];

    // zero all staging (rows 8..15 of every chunk must stay zero; h init = 0)
    {
        unsigned* p32 = (unsigned*)SMEM;
        for (int i = tid; i < SM_SHORTS / 2; i += 512) p32[i] = 0u;
    }
    __syncthreads();                                    // barrier #1

    const ushort_t* rb = SMEM + lane * 8;               // frag read base (all roles)
    const int rowb = (fr & 1) * 4 + ((fr >> 1) << 1);   // this lane's h row base (0,4,2,6)

    if (wv < 4) {
        // =================== layer0 role (waves 0..3) ===================
        s8v Bh[4][4], Bl[4][4];                         // [gate][kc]
        float bias[4];
#pragma unroll
        for (int g = 0; g < 4; ++g) {
            int n = g * 64 + wv * 16 + fc;
            bias[g] = b0[n];
#pragma unroll
            for (int kc = 0; kc < 4; ++kc)
                load_bfrag(W0, U0, 64, 128, 256, kc * 32 + fr * 8, n, Bh[g][kc], Bl[g][kc]);
        }
#pragma unroll
        for (int g = 0; g < 4; ++g) {
            PIN(bias[g]);
#pragma unroll
            for (int kc = 0; kc < 4; ++kc) { PIN(Bh[g][kc]); PIN(Bl[g][kc]); }
        }
        float c0[2] = {0.f, 0.f};
        const int hq  = wv >> 1;                        // h0 chunk this wave writes
        const int k   = (wv & 1) * 16 + fc;             // k within chunk
        const int ibw = (k >> 3) * 128 + (k & 7);       // lane-dep write offset
        __syncthreads();                                // barrier #2
        for (int s = 0; s < T_STEPS + 2; ++s) {
            if (s < T_STEPS) {
                const ushort_t* r = rb + ((s & 1) << 10);   // parity*1024 shorts
                s8v ah[4], al[4];
                ah[0] = *(const s8v*)&r[XH  +   0];
                al[0] = *(const s8v*)&r[XL  +   0];
                ah[1] = *(const s8v*)&r[XH  + 512];
                al[1] = *(const s8v*)&r[XL  + 512];
                ah[2] = *(const s8v*)&r[H0H +   0];
                al[2] = *(const s8v*)&r[H0L +   0];
                ah[3] = *(const s8v*)&r[H0H + 512];
                al[3] = *(const s8v*)&r[H0L + 512];
                f4v acc[4];
#pragma unroll
                for (int g = 0; g < 4; ++g) acc[g] = (f4v){bias[g], bias[g], bias[g], bias[g]};
                // same-acc distance 4: latency hidden by the 4 independent g chains
#pragma unroll
                for (int kc = 0; kc < 4; ++kc) {
#pragma unroll
                    for (int g = 0; g < 4; ++g)
                        acc[g] = __builtin_amdgcn_mfma_f32_16x16x32_bf16(ah[kc], Bh[g][kc], acc[g], 0, 0, 0);
#pragma unroll
                    for (int g = 0; g < 4; ++g)
                        acc[g] = __builtin_amdgcn_mfma_f32_16x16x32_bf16(al[kc], Bh[g][kc], acc[g], 0, 0, 0);
#pragma unroll
                    for (int g = 0; g < 4; ++g)
                        acc[g] = __builtin_amdgcn_mfma_f32_16x16x32_bf16(ah[kc], Bl[g][kc], acc[g], 0, 0, 0);
                }
                float hn[2];
                gates2(acc, c0, hn);
                {
                    ushort_t* w = SMEM + (((s & 1) ^ 1) << 10) + hq * 512 + ibw;
#pragma unroll
                    for (int j = 0; j < 2; ++j) {
                        unsigned short hh_, ll_;
                        tsplit(hn[j], hh_, ll_);
                        w[H0H + (rowb + j) * 8] = hh_;
                        w[H0L + (rowb + j) * 8] = ll_;
                    }
                }
            }
            BAR();
        }
    } else if (wv < 6) {
        // =================== layer1 role (waves 4,5) ===================
        s8v Bh[4][3], Bl[4][3];
        float bias[4];
#pragma unroll
        for (int g = 0; g < 4; ++g) {
            int n = g * 32 + (wv & 1) * 16 + fc;
            bias[g] = b1[n];
#pragma unroll
            for (int kc = 0; kc < 3; ++kc)
                load_bfrag(W1, U1, 64, 96, 128, kc * 32 + fr * 8, n, Bh[g][kc], Bl[g][kc]);
        }
#pragma unroll
        for (int g = 0; g < 4; ++g) {
            PIN(bias[g]);
#pragma unroll
            for (int kc = 0; kc < 3; ++kc) { PIN(Bh[g][kc]); PIN(Bl[g][kc]); }
        }
        float c1[2] = {0.f, 0.f};
        const int k   = (wv & 1) * 16 + fc;
        const int ibw = (k >> 3) * 128 + (k & 7);
        __syncthreads();                                // barrier #2
        for (int s = 0; s < T_STEPS + 2; ++s) {
            if (s >= 1 && s <= T_STEPS) {
                const int p = s & 1;
                const ushort_t* r  = rb + (p << 10);    // H0 parity stride 1024
                const ushort_t* r1 = rb + (p << 9);     // H1 parity stride 512
                s8v ah[3], al[3];
                ah[0] = *(const s8v*)&r[H0H +   0];
                al[0] = *(const s8v*)&r[H0L +   0];
                ah[1] = *(const s8v*)&r[H0H + 512];
                al[1] = *(const s8v*)&r[H0L + 512];
                ah[2] = *(const s8v*)&r1[H1H];
                al[2] = *(const s8v*)&r1[H1L];
                f4v acc[4];
#pragma unroll
                for (int g = 0; g < 4; ++g) acc[g] = (f4v){bias[g], bias[g], bias[g], bias[g]};
#pragma unroll
                for (int kc = 0; kc < 3; ++kc) {
#pragma unroll
                    for (int g = 0; g < 4; ++g)
                        acc[g] = __builtin_amdgcn_mfma_f32_16x16x32_bf16(ah[kc], Bh[g][kc], acc[g], 0, 0, 0);
#pragma unroll
                    for (int g = 0; g < 4; ++g)
                        acc[g] = __builtin_amdgcn_mfma_f32_16x16x32_bf16(al[kc], Bh[g][kc], acc[g], 0, 0, 0);
#pragma unroll
                    for (int g = 0; g < 4; ++g)
                        acc[g] = __builtin_amdgcn_mfma_f32_16x16x32_bf16(ah[kc], Bl[g][kc], acc[g], 0, 0, 0);
                }
                float hn[2];
                gates2(acc, c1, hn);
                {
                    ushort_t* w = SMEM + ((p ^ 1) << 9) + ibw;
#pragma unroll
                    for (int j = 0; j < 2; ++j) {
                        unsigned short hh_, ll_;
                        tsplit(hn[j], hh_, ll_);
                        w[H1H + (rowb + j) * 8] = hh_;
                        w[H1L + (rowb + j) * 8] = ll_;
                    }
                }
            }
            BAR();
        }
    } else if (wv == 6) {
        // =================== layer2 role (wave 6) ===================
        s8v Bh[4][2], Bl[4][2];
        float bias[4];
#pragma unroll
        for (int g = 0; g < 4; ++g) {
            int n = g * 16 + fc;
            bias[g] = b2[n];
#pragma unroll
            for (int kc = 0; kc < 2; ++kc)
                load_bfrag(W2, U2, 32, 48, 64, kc * 32 + fr * 8, n, Bh[g][kc], Bl[g][kc]);
        }
#pragma unroll
        for (int g = 0; g < 4; ++g) {
            PIN(bias[g]);
#pragma unroll
            for (int kc = 0; kc < 2; ++kc) { PIN(Bh[g][kc]); PIN(Bl[g][kc]); }
        }
        float c2[2] = {0.f, 0.f};
        const int ibw = (fc >> 3) * 128 + (fc & 7);     // k = fc (0..15)
        __syncthreads();                                // barrier #2
        for (int s = 0; s < T_STEPS + 2; ++s) {
            if (s >= 2) {
                const int p = s & 1;
                const ushort_t* r1 = rb + (p << 9);     // H1,H2 parity stride 512
                s8v ah[2], al[2];
                ah[0] = *(const s8v*)&r1[H1H];
                al[0] = *(const s8v*)&r1[H1L];
                ah[1] = *(const s8v*)&r1[H2H];
                al[1] = *(const s8v*)&r1[H2L];
                f4v acc[4];
#pragma unroll
                for (int g = 0; g < 4; ++g) acc[g] = (f4v){bias[g], bias[g], bias[g], bias[g]};
#pragma unroll
                for (int kc = 0; kc < 2; ++kc) {
#pragma unroll
                    for (int g = 0; g < 4; ++g)
                        acc[g] = __builtin_amdgcn_mfma_f32_16x16x32_bf16(ah[kc], Bh[g][kc], acc[g], 0, 0, 0);
#pragma unroll
                    for (int g = 0; g < 4; ++g)
                        acc[g] = __builtin_amdgcn_mfma_f32_16x16x32_bf16(al[kc], Bh[g][kc], acc[g], 0, 0, 0);
#pragma unroll
                    for (int g = 0; g < 4; ++g)
                        acc[g] = __builtin_amdgcn_mfma_f32_16x16x32_bf16(ah[kc], Bl[g][kc], acc[g], 0, 0, 0);
                }
                float hn[2];
                gates2(acc, c2, hn);
                {
                    ushort_t* w = SMEM + ((p ^ 1) << 9) + ibw;
#pragma unroll
                    for (int j = 0; j < 2; ++j) {
                        unsigned short hh_, ll_;
                        tsplit(hn[j], hh_, ll_);
                        w[H2H + (rowb + j) * 8] = hh_;
                        w[H2L + (rowb + j) * 8] = ll_;
                    }
                    if (s == T_STEPS + 1) {             // t2 = 255: final h2
#pragma unroll
                        for (int j = 0; j < 2; ++j) h2last[rowb + j][fc] = hn[j];
                    }
                }
            }
            BAR();
        }
    } else {
        // =================== x-stager role (wave 7), 2-deep pipeline ===================
        const int xb = lane >> 3;                       // batch row 0..7
        const int fo = (lane & 7) * 8;                  // feature octet base
        const float* xp = x + ((size_t)(bbase + xb) * T_STEPS) * 64 + fo;
        const int o2 = (fo >> 5) * 512 + (((fo & 31) >> 3) * 16 + xb) * 8;

        auto write_x = [&](float4 v0, float4 v1, int tt) {
            float vv[8] = {v0.x, v0.y, v0.z, v0.w, v1.x, v1.y, v1.z, v1.w};
            s8v hi8, lo8;
#pragma unroll
            for (int j = 0; j < 8; ++j) {
                unsigned short h_, l_;
                tsplit(vv[j], h_, l_);
                hi8[j] = (short)h_;
                lo8[j] = (short)l_;
            }
            ushort_t* wbp = SMEM + ((tt & 1) << 10) + o2;
            *(s8v*)&wbp[XH] = hi8;
            *(s8v*)&wbp[XL] = lo8;
        };

        // prologue: write x(0), prefetch x(1) into regs
        float4 pa = *(const float4*)(xp);
        float4 pb = *(const float4*)(xp + 4);
        write_x(pa, pb, 0);
        pa = *(const float4*)(xp + 64);
        pb = *(const float4*)(xp + 64 + 4);
        __syncthreads();                                // barrier #2
        for (int s = 0; s < T_STEPS + 2; ++s) {
            float4 na, nb;
            const bool ld = (s + 2 < T_STEPS);
            if (ld) {                                   // issue x(s+2) early
                na = *(const float4*)(xp + (size_t)(s + 2) * 64);
                nb = *(const float4*)(xp + (size_t)(s + 2) * 64 + 4);
            }
            if (s + 1 < T_STEPS) write_x(pa, pb, s + 1);   // waits on load from s-1
            if (ld) { pa = na; pb = nb; }
            BAR();
        }
    }

    __syncthreads();
    // =================== dense head ===================
    if (tid < BT) {
        float acc = bd[0];
#pragma unroll
        for (int j = 0; j < 16; ++j) acc += h2last[tid][j] * Wd[j];
        out[bbase + tid] = acc;
    }
}

extern "C" void kernel_launch(void* const* d_in, const int* in_sizes, int n_in,
                              void* d_out, int out_size, void* d_ws, size_t ws_size,
                              hipStream_t stream) {
    (void)in_sizes; (void)n_in; (void)d_ws; (void)ws_size; (void)out_size;
    const float* x  = (const float*)d_in[0];
    const float* W0 = (const float*)d_in[1];
    const float* U0 = (const float*)d_in[2];
    const float* b0 = (const float*)d_in[3];
    const float* W1 = (const float*)d_in[4];
    const float* U1 = (const float*)d_in[5];
    const float* b1 = (const float*)d_in[6];
    const float* W2 = (const float*)d_in[7];
    const float* U2 = (const float*)d_in[8];
    const float* b2 = (const float*)d_in[9];
    const float* Wd = (const float*)d_in[10];
    const float* bd = (const float*)d_in[11];
    float* out = (float*)d_out;

    dim3 grid(2048 / BT);   // 256 blocks, 1 per CU
    dim3 block(512);        // 8 waves, 2 per SIMD
    hipLaunchKernelGGL(lstm_pipe, grid, block, 0, stream,
                       x, W0, U0, b0, W1, U1, b1, W2, U2, b2, Wd, bd, out);
}

// Round 10
// 406.949 us; speedup vs baseline: 4.2103x; 1.0188x over previous
//
#include <hip/hip_runtime.h>

// Fused 3-layer LSTM + dense head, layer-pipelined wave specialization.
// B=2048, T=256, F=64, H=[64,32,16], OUT=1. fp32 in/out.
//
// bf16 3-term split MFMA (ah*wh + al*wh + ah*wl) for ~2^-16 precision.
// Block = 512 threads = 8 waves, grid = 256 (1 block/CU, BT=8 batches).
//   waves 0-3 : layer0 at step t    waves 4-5 : layer1 at t-1
//   wave  6   : layer2 at t-2       wave  7   : x-stager
//
// Round-16: base = R9 (298us counters; permlane gates). New: 2-timestep
// x-batching INSIDE the L0 waves. x(2c) staged in rows 0-7, x(2c+1) in rows
// 8-15 of one chunk; even steps compute the x*W0 part for BOTH timesteps at
// full 16-row MFMA utilization (24 MFMAs cover 2 steps, was 24/step with
// rows 8-15 wasted). h*U0 accumulates on top: h-staging rows 8-15 are zero,
// so rows 8-15 of the acc carry z_x(2c+1) through the even step exactly.
// Odd step: 16 permlane32_swap(r1) move rows 8-15 -> rows 0-7 as C-init;
// no x-reads, no x-MFMAs. Accumulation order per output unchanged
// (bias,kc0,kc1,[+0 exact],kc2,kc3) -> bit-identical absmax.
// Bottleneck SIMDs (L0+L1) drop 84 -> avg 72 MFMA/step; odd steps save
// 4 ds_read_b128. Failed-branch ledger: z_x producer wave (R3/R6, compiler
// re-serializes LDS-fed MFMA), setprio+split-acc (R7), 2 blocks/CU (R8,
// VGPR spill -> 3.1GB scratch).

typedef __attribute__((ext_vector_type(8))) short s8v;   // 8 x bf16
typedef __attribute__((ext_vector_type(4))) float f4v;   // 4 x f32
typedef __attribute__((ext_vector_type(2))) unsigned uint2v;
typedef unsigned short ushort_t;

#define T_STEPS 256
#define BT 8

// SMEM layout (units: shorts). chunk = [kgrp 0..3][row 0..15][j 0..7] = 512 shorts.
// X chunks: parity = (t>>1)&1 (2-timestep chunks; row = batch + 8*(t&1)).
#define XH  0       // [par][2 chunks], parity stride 1024
#define XL  2048
#define H0H 4096    // [par][2 chunks], parity stride 1024 (rows 8-15 zero)
#define H0L 6144
#define H1H 8192    // [par][1 chunk],  parity stride 512
#define H1L 9216
#define H2H 10240   // [par][1 chunk],  parity stride 512 (k 16..31 = zero pad)
#define H2L 11264
#define SM_SHORTS 12288

#define PIN(v) asm volatile("" : "+v"(v))
#define BAR()  asm volatile("s_waitcnt lgkmcnt(0)\n\ts_barrier" ::: "memory")

__device__ __forceinline__ unsigned short f2bf(float f) {      // RTNE (weights, one-time)
    unsigned u = __float_as_uint(f);
    u += 0x7fff + ((u >> 16) & 1);
    return (unsigned short)(u >> 16);
}
__device__ __forceinline__ float bf2f(unsigned short s) {
    return __uint_as_float(((unsigned)s) << 16);
}
// cheap truncation split: hi = top 16 bits, lo = trunc(v - hi). Error <= 2^-16*|v|.
__device__ __forceinline__ void tsplit(float v, unsigned short& hi, unsigned short& lo) {
    unsigned u = __float_as_uint(v);
    hi = (unsigned short)(u >> 16);
    float r = v - __uint_as_float(u & 0xffff0000u);   // exact
    lo = (unsigned short)(__float_as_uint(r) >> 16);
}
__device__ __forceinline__ float sigmoid_f(float x) {
    return __builtin_amdgcn_rcpf(1.0f + __expf(-x));
}
__device__ __forceinline__ float tanh_f(float x) {
    return 1.0f - 2.0f * __builtin_amdgcn_rcpf(__expf(2.0f * x) + 1.0f);
}

// z[lane] = lane<32 ? a[lane] : b[lane-32] -- result0 of v_permlane32_swap_b32.
__device__ __forceinline__ float sel_swap(float a, float b) {
    uint2v r = __builtin_amdgcn_permlane32_swap(__float_as_uint(a), __float_as_uint(b), false, false);
    return __uint_as_float(r[0]);
}
// z[lane<32] = a[lane+32] (high half pulled down); high lanes keep own value.
// result1 of swap(a,a): r1[0:31]=a[32:63], r1[32:63]=a[32:63].
__device__ __forceinline__ float swap_hi(float a) {
    uint2v r = __builtin_amdgcn_permlane32_swap(__float_as_uint(a), __float_as_uint(a), false, false);
    return __uint_as_float(r[1]);
}

// combined [W;U] weight element, zero-padded past KH rows
__device__ __forceinline__ float wval(const float* W, const float* U,
                                      int inDim, int KH, int fourH, int k, int n) {
    if (k < inDim) return W[k * fourH + n];
    if (k < KH)    return U[(k - inDim) * fourH + n];
    return 0.0f;
}
__device__ __forceinline__ void load_bfrag(const float* W, const float* U,
                                           int inDim, int KH, int fourH,
                                           int k0, int n, s8v& hi, s8v& lo) {
#pragma unroll
    for (int j = 0; j < 8; ++j) {
        float w = wval(W, U, inDim, KH, fourH, k0 + j, n);
        unsigned short h = f2bf(w);
        unsigned short l = f2bf(w - bf2f(h));
        hi[j] = (short)h;
        lo[j] = (short)l;
    }
}

// Gate math on 2 rows/lane after full-wave redistribution:
//   low lanes (fr<2)  : own regs {0,1}       -> rows fr*4 + {0,1}
//   high lanes (fr>=2): partner regs {2,3}   -> rows (fr-2)*4 + {2,3}
// permlane32_swap does the low/high select in-register (no LDS pipe).
__device__ __forceinline__ void gates2(const f4v* acc, float* c, float* hn) {
#pragma unroll
    for (int j = 0; j < 2; ++j) {
        float zi = sel_swap(acc[0][j], acc[0][j + 2]);
        float zf = sel_swap(acc[1][j], acc[1][j + 2]);
        float zg = sel_swap(acc[2][j], acc[2][j + 2]);
        float zo = sel_swap(acc[3][j], acc[3][j + 2]);
        float ig = sigmoid_f(zi);
        float fg = sigmoid_f(zf);
        float gg = tanh_f(zg);
        float og = sigmoid_f(zo);
        c[j] = fmaf(fg, c[j], ig * gg);
        hn[j] = og * tanh_f(c[j]);
    }
}

__global__ __attribute__((amdgpu_flat_work_group_size(512, 512),
                          amdgpu_waves_per_eu(2, 2)))
void lstm_pipe(const float* __restrict__ x,
               const float* __restrict__ W0, const float* __restrict__ U0, const float* __restrict__ b0,
               const float* __restrict__ W1, const float* __restrict__ U1, const float* __restrict__ b1,
               const float* __restrict__ W2, const float* __restrict__ U2, const float* __restrict__ b2,
               const float* __restrict__ Wd, const float* __restrict__ bd,
               float* __restrict__ out)
{
    const int tid  = threadIdx.x;
    const int lane = tid & 63;
    const int wv   = tid >> 6;          // 0..7
    const int fr   = lane >> 4;         // k-group / C row-group
    const int fc   = lane & 15;         // frag column
    const int bbase = blockIdx.x * BT;

    __shared__ __align__(16) ushort_t SMEM[SM_SHORTS];
    __shared__ __align__(16) float h2last[BT][16];

    // zero all staging (h rows 8..15 must stay zero; h init = 0)
    {
        unsigned* p32 = (unsigned*)SMEM;
        for (int i = tid; i < SM_SHORTS / 2; i += 512) p32[i] = 0u;
    }
    __syncthreads();                                    // barrier #1

    const ushort_t* rb = SMEM + lane * 8;               // frag read base (all roles)
    const int rowb = (fr & 1) * 4 + ((fr >> 1) << 1);   // this lane's h row base (0,4,2,6)

    if (wv < 4) {
        // =================== layer0 role (waves 0..3) ===================
        s8v Bh[4][4], Bl[4][4];                         // [gate][kc]; kc0,1 = W0, kc2,3 = U0
        float bias[4];
#pragma unroll
        for (int g = 0; g < 4; ++g) {
            int n = g * 64 + wv * 16 + fc;
            bias[g] = b0[n];
#pragma unroll
            for (int kc = 0; kc < 4; ++kc)
                load_bfrag(W0, U0, 64, 128, 256, kc * 32 + fr * 8, n, Bh[g][kc], Bl[g][kc]);
        }
#pragma unroll
        for (int g = 0; g < 4; ++g) {
            PIN(bias[g]);
#pragma unroll
            for (int kc = 0; kc < 4; ++kc) { PIN(Bh[g][kc]); PIN(Bl[g][kc]); }
        }
        float c0[2] = {0.f, 0.f};
        const int hq  = wv >> 1;                        // h0 chunk this wave writes
        const int k   = (wv & 1) * 16 + fc;             // k within chunk
        const int ibw = (k >> 3) * 128 + (k & 7);       // lane-dep write offset
        f4v acc[4];                                     // live across steps (carries z_x odd)
        __syncthreads();                                // barrier #2
        for (int s = 0; s < T_STEPS + 2; ++s) {
            if (s < T_STEPS) {
                const int p = s & 1;
                const ushort_t* r = rb + (p << 10);     // H0 parity*1024 shorts
                s8v hh0 = *(const s8v*)&r[H0H +   0];
                s8v hl0 = *(const s8v*)&r[H0L +   0];
                s8v hh1 = *(const s8v*)&r[H0H + 512];
                s8v hl1 = *(const s8v*)&r[H0L + 512];
                if (p == 0) {
                    // even step: x-part for BOTH timesteps (rows 0-7 = t, 8-15 = t+1)
                    const ushort_t* rx = rb + (((s >> 1) & 1) << 10);
                    s8v xh0 = *(const s8v*)&rx[XH +   0];
                    s8v xl0 = *(const s8v*)&rx[XL +   0];
                    s8v xh1 = *(const s8v*)&rx[XH + 512];
                    s8v xl1 = *(const s8v*)&rx[XL + 512];
#pragma unroll
                    for (int g = 0; g < 4; ++g) acc[g] = (f4v){bias[g], bias[g], bias[g], bias[g]};
#pragma unroll
                    for (int g = 0; g < 4; ++g)
                        acc[g] = __builtin_amdgcn_mfma_f32_16x16x32_bf16(xh0, Bh[g][0], acc[g], 0, 0, 0);
#pragma unroll
                    for (int g = 0; g < 4; ++g)
                        acc[g] = __builtin_amdgcn_mfma_f32_16x16x32_bf16(xl0, Bh[g][0], acc[g], 0, 0, 0);
#pragma unroll
                    for (int g = 0; g < 4; ++g)
                        acc[g] = __builtin_amdgcn_mfma_f32_16x16x32_bf16(xh0, Bl[g][0], acc[g], 0, 0, 0);
#pragma unroll
                    for (int g = 0; g < 4; ++g)
                        acc[g] = __builtin_amdgcn_mfma_f32_16x16x32_bf16(xh1, Bh[g][1], acc[g], 0, 0, 0);
#pragma unroll
                    for (int g = 0; g < 4; ++g)
                        acc[g] = __builtin_amdgcn_mfma_f32_16x16x32_bf16(xl1, Bh[g][1], acc[g], 0, 0, 0);
#pragma unroll
                    for (int g = 0; g < 4; ++g)
                        acc[g] = __builtin_amdgcn_mfma_f32_16x16x32_bf16(xh1, Bl[g][1], acc[g], 0, 0, 0);
                } else {
                    // odd step: z_x(t) sits in rows 8-15 of prev acc -> pull to rows 0-7
#pragma unroll
                    for (int g = 0; g < 4; ++g)
#pragma unroll
                        for (int q = 0; q < 4; ++q) acc[g][q] = swap_hi(acc[g][q]);
                }
                // h*U0 accumulate (A rows 8-15 are zero -> rows 8-15 unchanged, exact)
#pragma unroll
                for (int g = 0; g < 4; ++g)
                    acc[g] = __builtin_amdgcn_mfma_f32_16x16x32_bf16(hh0, Bh[g][2], acc[g], 0, 0, 0);
#pragma unroll
                for (int g = 0; g < 4; ++g)
                    acc[g] = __builtin_amdgcn_mfma_f32_16x16x32_bf16(hl0, Bh[g][2], acc[g], 0, 0, 0);
#pragma unroll
                for (int g = 0; g < 4; ++g)
                    acc[g] = __builtin_amdgcn_mfma_f32_16x16x32_bf16(hh0, Bl[g][2], acc[g], 0, 0, 0);
#pragma unroll
                for (int g = 0; g < 4; ++g)
                    acc[g] = __builtin_amdgcn_mfma_f32_16x16x32_bf16(hh1, Bh[g][3], acc[g], 0, 0, 0);
#pragma unroll
                for (int g = 0; g < 4; ++g)
                    acc[g] = __builtin_amdgcn_mfma_f32_16x16x32_bf16(hl1, Bh[g][3], acc[g], 0, 0, 0);
#pragma unroll
                for (int g = 0; g < 4; ++g)
                    acc[g] = __builtin_amdgcn_mfma_f32_16x16x32_bf16(hh1, Bl[g][3], acc[g], 0, 0, 0);
                float hn[2];
                gates2(acc, c0, hn);
                {
                    ushort_t* w = SMEM + ((p ^ 1) << 10) + hq * 512 + ibw;
#pragma unroll
                    for (int j = 0; j < 2; ++j) {
                        unsigned short hh_, ll_;
                        tsplit(hn[j], hh_, ll_);
                        w[H0H + (rowb + j) * 8] = hh_;
                        w[H0L + (rowb + j) * 8] = ll_;
                    }
                }
            }
            BAR();
        }
    } else if (wv < 6) {
        // =================== layer1 role (waves 4,5) ===================
        s8v Bh[4][3], Bl[4][3];
        float bias[4];
#pragma unroll
        for (int g = 0; g < 4; ++g) {
            int n = g * 32 + (wv & 1) * 16 + fc;
            bias[g] = b1[n];
#pragma unroll
            for (int kc = 0; kc < 3; ++kc)
                load_bfrag(W1, U1, 64, 96, 128, kc * 32 + fr * 8, n, Bh[g][kc], Bl[g][kc]);
        }
#pragma unroll
        for (int g = 0; g < 4; ++g) {
            PIN(bias[g]);
#pragma unroll
            for (int kc = 0; kc < 3; ++kc) { PIN(Bh[g][kc]); PIN(Bl[g][kc]); }
        }
        float c1[2] = {0.f, 0.f};
        const int k   = (wv & 1) * 16 + fc;
        const int ibw = (k >> 3) * 128 + (k & 7);
        __syncthreads();                                // barrier #2
        for (int s = 0; s < T_STEPS + 2; ++s) {
            if (s >= 1 && s <= T_STEPS) {
                const int p = s & 1;
                const ushort_t* r  = rb + (p << 10);    // H0 parity stride 1024
                const ushort_t* r1 = rb + (p << 9);     // H1 parity stride 512
                s8v ah[3], al[3];
                ah[0] = *(const s8v*)&r[H0H +   0];
                al[0] = *(const s8v*)&r[H0L +   0];
                ah[1] = *(const s8v*)&r[H0H + 512];
                al[1] = *(const s8v*)&r[H0L + 512];
                ah[2] = *(const s8v*)&r1[H1H];
                al[2] = *(const s8v*)&r1[H1L];
                f4v acc[4];
#pragma unroll
                for (int g = 0; g < 4; ++g) acc[g] = (f4v){bias[g], bias[g], bias[g], bias[g]};
#pragma unroll
                for (int kc = 0; kc < 3; ++kc) {
#pragma unroll
                    for (int g = 0; g < 4; ++g)
                        acc[g] = __builtin_amdgcn_mfma_f32_16x16x32_bf16(ah[kc], Bh[g][kc], acc[g], 0, 0, 0);
#pragma unroll
                    for (int g = 0; g < 4; ++g)
                        acc[g] = __builtin_amdgcn_mfma_f32_16x16x32_bf16(al[kc], Bh[g][kc], acc[g], 0, 0, 0);
#pragma unroll
                    for (int g = 0; g < 4; ++g)
                        acc[g] = __builtin_amdgcn_mfma_f32_16x16x32_bf16(ah[kc], Bl[g][kc], acc[g], 0, 0, 0);
                }
                float hn[2];
                gates2(acc, c1, hn);
                {
                    ushort_t* w = SMEM + ((p ^ 1) << 9) + ibw;
#pragma unroll
                    for (int j = 0; j < 2; ++j) {
                        unsigned short hh_, ll_;
                        tsplit(hn[j], hh_, ll_);
                        w[H1H + (rowb + j) * 8] = hh_;
                        w[H1L + (rowb + j) * 8] = ll_;
                    }
                }
            }
            BAR();
        }
    } else if (wv == 6) {
        // =================== layer2 role (wave 6) ===================
        s8v Bh[4][2], Bl[4][2];
        float bias[4];
#pragma unroll
        for (int g = 0; g < 4; ++g) {
            int n = g * 16 + fc;
            bias[g] = b2[n];
#pragma unroll
            for (int kc = 0; kc < 2; ++kc)
                load_bfrag(W2, U2, 32, 48, 64, kc * 32 + fr * 8, n, Bh[g][kc], Bl[g][kc]);
        }
#pragma unroll
        for (int g = 0; g < 4; ++g) {
            PIN(bias[g]);
#pragma unroll
            for (int kc = 0; kc < 2; ++kc) { PIN(Bh[g][kc]); PIN(Bl[g][kc]); }
        }
        float c2[2] = {0.f, 0.f};
        const int ibw = (fc >> 3) * 128 + (fc & 7);     // k = fc (0..15)
        __syncthreads();                                // barrier #2
        for (int s = 0; s < T_STEPS + 2; ++s) {
            if (s >= 2) {
                const int p = s & 1;
                const ushort_t* r1 = rb + (p << 9);     // H1,H2 parity stride 512
                s8v ah[2], al[2];
                ah[0] = *(const s8v*)&r1[H1H];
                al[0] = *(const s8v*)&r1[H1L];
                ah[1] = *(const s8v*)&r1[H2H];
                al[1] = *(const s8v*)&r1[H2L];
                f4v acc[4];
#pragma unroll
                for (int g = 0; g < 4; ++g) acc[g] = (f4v){bias[g], bias[g], bias[g], bias[g]};
#pragma unroll
                for (int kc = 0; kc < 2; ++kc) {
#pragma unroll
                    for (int g = 0; g < 4; ++g)
                        acc[g] = __builtin_amdgcn_mfma_f32_16x16x32_bf16(ah[kc], Bh[g][kc], acc[g], 0, 0, 0);
#pragma unroll
                    for (int g = 0; g < 4; ++g)
                        acc[g] = __builtin_amdgcn_mfma_f32_16x16x32_bf16(al[kc], Bh[g][kc], acc[g], 0, 0, 0);
#pragma unroll
                    for (int g = 0; g < 4; ++g)
                        acc[g] = __builtin_amdgcn_mfma_f32_16x16x32_bf16(ah[kc], Bl[g][kc], acc[g], 0, 0, 0);
                }
                float hn[2];
                gates2(acc, c2, hn);
                {
                    ushort_t* w = SMEM + ((p ^ 1) << 9) + ibw;
#pragma unroll
                    for (int j = 0; j < 2; ++j) {
                        unsigned short hh_, ll_;
                        tsplit(hn[j], hh_, ll_);
                        w[H2H + (rowb + j) * 8] = hh_;
                        w[H2L + (rowb + j) * 8] = ll_;
                    }
                    if (s == T_STEPS + 1) {             // t2 = 255: final h2
#pragma unroll
                        for (int j = 0; j < 2; ++j) h2last[rowb + j][fc] = hn[j];
                    }
                }
            }
            BAR();
        }
    } else {
        // =================== x-stager role (wave 7) ===================
        // 2-timestep chunks: timestep tt -> parity (tt>>1)&1, row = xb + 8*(tt&1).
        // During step s, write tt = s+2; load x(s+3) for next step.
        const int xb = lane >> 3;                       // batch row 0..7
        const int fo = (lane & 7) * 8;                  // feature octet base
        const float* xp = x + ((size_t)(bbase + xb) * T_STEPS) * 64 + fo;
        const int o2 = (fo >> 5) * 512 + (((fo & 31) >> 3) * 16 + xb) * 8;

        auto write_x = [&](float4 v0, float4 v1, int tt) {
            float vv[8] = {v0.x, v0.y, v0.z, v0.w, v1.x, v1.y, v1.z, v1.w};
            s8v hi8, lo8;
#pragma unroll
            for (int j = 0; j < 8; ++j) {
                unsigned short h_, l_;
                tsplit(vv[j], h_, l_);
                hi8[j] = (short)h_;
                lo8[j] = (short)l_;
            }
            ushort_t* wbp = SMEM + (((tt >> 1) & 1) << 10) + ((tt & 1) << 6) + o2;
            *(s8v*)&wbp[XH] = hi8;
            *(s8v*)&wbp[XL] = lo8;
        };

        // prologue: chunk 0 = x(0) rows 0-7 + x(1) rows 8-15; preload x(2)
        float4 pa = *(const float4*)(xp);
        float4 pb = *(const float4*)(xp + 4);
        write_x(pa, pb, 0);
        pa = *(const float4*)(xp + 64);
        pb = *(const float4*)(xp + 64 + 4);
        write_x(pa, pb, 1);
        pa = *(const float4*)(xp + 128);
        pb = *(const float4*)(xp + 128 + 4);
        __syncthreads();                                // barrier #2
        for (int s = 0; s < T_STEPS + 2; ++s) {
            float4 na, nb;
            const bool ld = (s + 3 < T_STEPS);
            if (ld) {                                   // issue x(s+3) early
                na = *(const float4*)(xp + (size_t)(s + 3) * 64);
                nb = *(const float4*)(xp + (size_t)(s + 3) * 64 + 4);
            }
            if (s + 2 < T_STEPS) write_x(pa, pb, s + 2);   // uses load from s-1
            if (ld) { pa = na; pb = nb; }
            BAR();
        }
    }

    __syncthreads();
    // =================== dense head ===================
    if (tid < BT) {
        float acc = bd[0];
#pragma unroll
        for (int j = 0; j < 16; ++j) acc += h2last[tid][j] * Wd[j];
        out[bbase + tid] = acc;
    }
}

extern "C" void kernel_launch(void* const* d_in, const int* in_sizes, int n_in,
                              void* d_out, int out_size, void* d_ws, size_t ws_size,
                              hipStream_t stream) {
    (void)in_sizes; (void)n_in; (void)d_ws; (void)ws_size; (void)out_size;
    const float* x  = (const float*)d_in[0];
    const float* W0 = (const float*)d_in[1];
    const float* U0 = (const float*)d_in[2];
    const float* b0 = (const float*)d_in[3];
    const float* W1 = (const float*)d_in[4];
    const float* U1 = (const float*)d_in[5];
    const float* b1 = (const float*)d_in[6];
    const float* W2 = (const float*)d_in[7];
    const float* U2 = (const float*)d_in[8];
    const float* b2 = (const float*)d_in[9];
    const float* Wd = (const float*)d_in[10];
    const float* bd = (const float*)d_in[11];
    float* out = (float*)d_out;

    dim3 grid(2048 / BT);   // 256 blocks, 1 per CU
    dim3 block(512);        // 8 waves, 2 per SIMD
    hipLaunchKernelGGL(lstm_pipe, grid, block, 0, stream,
                       x, W0, U0, b0, W1, U1, b1, W2, U2, b2, Wd, bd, out);
}